// Round 12
// baseline (266.949 us; speedup 1.0000x reference)
//
#include <hip/hip_runtime.h>
#include <stdint.h>
#include <type_traits>

#define S_LEN 2048
#define DM 2048
#define NH 16
#define DKH 128
#define NB 2
#define NROWS (NB * S_LEN)  // 4096

typedef unsigned short u16;
typedef __attribute__((ext_vector_type(8))) __bf16 bf16x8;
typedef __attribute__((ext_vector_type(4))) float f32x4;

__device__ __forceinline__ float bf2f(u16 u) {
  union { unsigned u; float f; } v; v.u = ((unsigned)u) << 16; return v.f;
}
__device__ __forceinline__ u16 f2bf(float f) {
  union { float f; unsigned u; } v; v.f = f;
  unsigned r = v.u + 0x7FFFu + ((v.u >> 16) & 1u);
  return (u16)(r >> 16);
}

// async global->LDS, 16B per lane. lds = WAVE-UNIFORM chunk base (HW adds lane*16);
// g = PER-LANE global address.
__device__ __forceinline__ void async_copy16(void* lds, const void* g) {
  __builtin_amdgcn_global_load_lds(
      (const __attribute__((address_space(1))) unsigned int*)g,
      (__attribute__((address_space(3))) unsigned int*)lds, 16, 0, 0);
}

// ---------------- fused cast fp32 -> bf16 for all 5 inputs ----------------
__global__ void cast_all_kernel(const float* __restrict__ x, const float* __restrict__ wq,
                                const float* __restrict__ wk, const float* __restrict__ wv,
                                const float* __restrict__ wo, u16* __restrict__ xb,
                                u16* __restrict__ wqkv, u16* __restrict__ wob) {
  const int XN4 = NROWS * DM / 4;  // 2^21
  const int WN4 = DM * DM / 4;     // 2^20
  int total = XN4 + 4 * WN4;
  int stride = gridDim.x * blockDim.x;
  for (int i = blockIdx.x * blockDim.x + threadIdx.x; i < total; i += stride) {
    const float* s;
    u16* d;
    int j;
    if (i < XN4) {
      s = x; d = xb; j = i;
    } else {
      int k = i - XN4;
      int w = k >> 20;
      j = k & 0xFFFFF;
      if (w == 0) { s = wq; d = wqkv; }
      else if (w == 1) { s = wk; d = wqkv + (size_t)DM * DM; }
      else if (w == 2) { s = wv; d = wqkv + (size_t)2 * DM * DM; }
      else { s = wo; d = wob; }
    }
    float4 v = ((const float4*)s)[j];
    unsigned r0 = (unsigned)f2bf(v.x) | ((unsigned)f2bf(v.y) << 16);
    unsigned r1 = (unsigned)f2bf(v.z) | ((unsigned)f2bf(v.w) << 16);
    ((uint2*)d)[j] = make_uint2(r0, r1);
  }
}

// ---------------- RoPE cos/sin table: float2[S][64] ----------------
__global__ void rope_table_kernel(float2* __restrict__ ctab) {
  int idx = blockIdx.x * blockDim.x + threadIdx.x;
  if (idx >= S_LEN * 64) return;
  int s = idx >> 6, i = idx & 63;
  float inv = expf(-9.210340371976184f * (float)i * (1.0f / 64.0f));
  float fr = (float)s * inv;
  ctab[idx] = make_float2(cosf(fr), sinf(fr));
}

// ================= 256 x (64*NSEG) 8-phase GEMM (r8 K-loop) =================
// EPI 0: f32 row-major out (Wo; standard XCD swizzle).
// EPI 2: QKV fused (NSEG=3, grid 32x16):
//   - COLUMN-CLUSTER XCD swizzle: XCD k owns tn in [4k,4k+4) x all tm ->
//     per-XCD B footprint 3MB (L2-resident) instead of 25MB streamed.
//   - mat0 (Q): plain bf16 lane-paired stores (RoPE applied inside attn).
//   - mat1 (K): RoPE in-epilogue, lane-paired stores.
//   - mat2 (V): transposed Vt[(b*16+h)*128+d][s], lg-paired uint4 stores.
template <int NSEG, int EPI>
__global__ __launch_bounds__(512, 1) void gemm256_kernel(const u16* __restrict__ A,
                                                         const u16* __restrict__ B,
                                                         void* __restrict__ C0,
                                                         void* __restrict__ C1,
                                                         void* __restrict__ C2,
                                                         const float2* __restrict__ ctab,
                                                         int M, int N, int Kd) {
  constexpr int BN = 64 * NSEG;
  constexpr int BSZ = BN * 128;  // bytes per B buffer
  constexpr int LDS_AE = 0, LDS_AO = 32768, LDS_BE = 65536, LDS_BO = 65536 + BSZ;

  extern __shared__ char smem[];
  u16* lds = (u16*)smem;

  int tid = threadIdx.x;
  int lane = tid & 63, wave = tid >> 6;
  int lr = lane & 15, lg = lane >> 4;
  int wm = wave >> 2, wn = wave & 3;

  int gx = gridDim.x, nwg = gx * gridDim.y;
  int bid = blockIdx.y * gx + blockIdx.x;
  int tmI, tnI;
  if constexpr (EPI == 2) {
    // column-cluster: XCD k = bid&7 owns tn 4k..4k+3 across all 16 tm (512 blocks)
    int k = bid & 7, j = bid >> 3;  // j 0..63
    tmI = j & 15;
    tnI = k * 4 + (j >> 4);
  } else {
    int cpx = nwg >> 3;
    int swz = (bid & 7) * cpx + (bid >> 3);
    tmI = swz / gx;
    tnI = swz % gx;
  }
  int tm = tmI * 256, tn = tnI * BN;

  int srow_in = lane >> 3;                             // 0..7
  int scolb = ((lane & 7) * 16) ^ ((lane >> 3) << 4);  // pre-swizzled src byte-col

  const u16* Arows = A + (size_t)tm * Kd;
  const u16* Brows = B + (size_t)tn * Kd;

  auto stageA = [&](int aBase, int h, int kt) {  // half h = 128 rows, 2 loads
#pragma unroll
    for (int l = 0; l < 2; l++) {
      int ch = h * 16 + l * 8 + wave;
      async_copy16(lds + ((aBase + ch * 1024) >> 1),
                   Arows + (size_t)(ch * 8 + srow_in) * Kd + kt * 64 + (scolb >> 1));
    }
  };
  auto stageB = [&](int bBase, int s, int kt) {  // seg s = 64 rows, 1 load
    int ch = s * 8 + wave;
    async_copy16(lds + ((bBase + ch * 1024) >> 1),
                 Brows + (size_t)(ch * 8 + srow_in) * Kd + kt * 64 + (scolb >> 1));
  };

  int acolb[2];
#pragma unroll
  for (int ks = 0; ks < 2; ks++) acolb[ks] = (ks * 64 + lg * 16) ^ ((lr & 7) << 4);
  int aBaseW = wm * 128 * 128;
  int brow_b = (wn * 16 * NSEG + lr) * 128;

  f32x4 zero4 = {0.f, 0.f, 0.f, 0.f};
  f32x4 acc[8][NSEG];
#pragma unroll
  for (int i = 0; i < 8; i++)
#pragma unroll
    for (int j = 0; j < NSEG; j++) acc[i][j] = zero4;

  bf16x8 bpre[NSEG][2];
  bf16x8 af[2][2];

  auto loadB = [&](int bBase) {
#pragma unroll
    for (int nf = 0; nf < NSEG; nf++)
#pragma unroll
      for (int ks = 0; ks < 2; ks++)
        bpre[nf][ks] = *(const bf16x8*)&lds[(bBase + brow_b + nf * 2048 + acolb[ks]) >> 1];
  };
  auto readA = [&](int aBase, int q) {
#pragma unroll
    for (int dm = 0; dm < 2; dm++)
#pragma unroll
      for (int ks = 0; ks < 2; ks++)
        af[dm][ks] = *(const bf16x8*)&lds[(aBase + aBaseW + (2 * q + dm) * 2048 + lr * 128 +
                                           acolb[ks]) >> 1];
  };
  auto mfmaC = [&](auto qc) {
    constexpr int Q = decltype(qc)::value;
    __builtin_amdgcn_s_setprio(1);
#pragma unroll
    for (int dm = 0; dm < 2; dm++)
#pragma unroll
      for (int nf = 0; nf < NSEG; nf++)
#pragma unroll
        for (int ks = 0; ks < 2; ks++)
          acc[2 * Q + dm][nf] = __builtin_amdgcn_mfma_f32_16x16x32_bf16(
              af[dm][ks], bpre[nf][ks], acc[2 * Q + dm][nf], 0, 0, 0);
    __builtin_amdgcn_s_setprio(0);
  };
  auto bar_pre = [&]() {
    __builtin_amdgcn_s_barrier();
    asm volatile("s_waitcnt lgkmcnt(0)" ::: "memory");
    __builtin_amdgcn_sched_barrier(0);
  };
  auto vm_wait = [&]() {
    if constexpr (NSEG == 3) asm volatile("s_waitcnt vmcnt(3)" ::: "memory");
    else asm volatile("s_waitcnt vmcnt(2)" ::: "memory");
  };

  int nk = Kd >> 6;
  int nIter = nk >> 1;

  stageA(LDS_AE, 0, 0);
  stageA(LDS_AE, 1, 0);
#pragma unroll
  for (int s = 0; s < NSEG; s++) stageB(LDS_BE, s, 0);
#pragma unroll
  for (int s = 0; s < NSEG; s++) stageB(LDS_BO, s, 1);
  vm_wait();
  __builtin_amdgcn_s_barrier();

  for (int i = 0; i < nIter; i++) {
    int tO = 2 * i + 1;
    int tE2 = 2 * i + 2; if (tE2 > nk - 1) tE2 = nk - 1;
    int tO2 = 2 * i + 3; if (tO2 > nk - 1) tO2 = nk - 1;

    // ---- ph0 ----
    loadB(LDS_BE); readA(LDS_AE, 0);
    stageA(LDS_AO, 0, tO);
    asm volatile("s_waitcnt lgkmcnt(8)" ::: "memory");
    bar_pre();
    mfmaC(std::integral_constant<int, 0>{});
    __builtin_amdgcn_s_barrier();
    // ---- ph1 ----
    readA(LDS_AE, 1);
    stageA(LDS_AO, 1, tO);
    bar_pre();
    mfmaC(std::integral_constant<int, 1>{});
    __builtin_amdgcn_s_barrier();
    // ---- ph2 ----
    readA(LDS_AE, 2);
    stageB(LDS_BE, 0, tE2);
    if constexpr (NSEG == 3) stageB(LDS_BE, 1, tE2);
    bar_pre();
    mfmaC(std::integral_constant<int, 2>{});
    __builtin_amdgcn_s_barrier();
    // ---- ph3 ----
    readA(LDS_AE, 3);
    stageB(LDS_BE, NSEG - 1, tE2);
    vm_wait();
    bar_pre();
    mfmaC(std::integral_constant<int, 3>{});
    __builtin_amdgcn_s_barrier();
    // ---- ph4 ----
    loadB(LDS_BO); readA(LDS_AO, 0);
    stageA(LDS_AE, 0, tE2);
    asm volatile("s_waitcnt lgkmcnt(8)" ::: "memory");
    bar_pre();
    mfmaC(std::integral_constant<int, 0>{});
    __builtin_amdgcn_s_barrier();
    // ---- ph5 ----
    readA(LDS_AO, 1);
    stageA(LDS_AE, 1, tE2);
    bar_pre();
    mfmaC(std::integral_constant<int, 1>{});
    __builtin_amdgcn_s_barrier();
    // ---- ph6 ----
    readA(LDS_AO, 2);
    stageB(LDS_BO, 0, tO2);
    if constexpr (NSEG == 3) stageB(LDS_BO, 1, tO2);
    bar_pre();
    mfmaC(std::integral_constant<int, 2>{});
    __builtin_amdgcn_s_barrier();
    // ---- ph7 ----
    readA(LDS_AO, 3);
    stageB(LDS_BO, NSEG - 1, tO2);
    vm_wait();
    bar_pre();
    mfmaC(std::integral_constant<int, 3>{});
    __builtin_amdgcn_s_barrier();
  }

  asm volatile("s_waitcnt vmcnt(0)" ::: "memory");

  // ---- epilogue ----
#pragma unroll
  for (int mf = 0; mf < 8; mf++) {
    int row = tm + wm * 128 + mf * 16 + lg * 4;
#pragma unroll
    for (int nf = 0; nf < NSEG; nf++) {
      int col = tn + wn * 16 * NSEG + nf * 16 + lr;
      if constexpr (EPI == 0) {
        float* O = (float*)C0;
#pragma unroll
        for (int r = 0; r < 4; r++) O[(size_t)(row + r) * N + col] = acc[mf][nf][r];
      } else {
        int mat = col >> 11, lc = col & 2047;  // frag-uniform (16-col frags)
        if (mat == 0) {
          // Q: plain bf16 lane-paired (RoPE applied inside attn)
          u16* O = (u16*)C0;
#pragma unroll
          for (int r = 0; r < 4; r++) {
            float a = acc[mf][nf][r];
            float b = __shfl_xor(a, 1);
            if (!(lr & 1)) {
              unsigned w = (unsigned)f2bf(a) | ((unsigned)f2bf(b) << 16);
              *(unsigned*)(O + (size_t)(row + r) * 2048 + lc) = w;
            }
          }
        } else if (mat == 1) {
          // K: RoPE in-epilogue, lane-paired stores
          u16* O = (u16*)C1;
          int d = lc & 127;
          bool odd = (d & 1) != 0;
          const float2* ct = ctab + (d >> 1);
#pragma unroll
          for (int r = 0; r < 4; r++) {
            float a = acc[mf][nf][r];
            float pp = __shfl_xor(a, 1);
            float2 cs = ct[((row + r) & (S_LEN - 1)) * 64];
            float o = odd ? (pp * cs.y + a * cs.x) : (a * cs.x - pp * cs.y);
            float ob = __shfl_xor(o, 1);
            if (!(lr & 1)) {
              unsigned w = (unsigned)f2bf(o) | ((unsigned)f2bf(ob) << 16);
              *(unsigned*)(O + (size_t)(row + r) * 2048 + lc) = w;
            }
          }
        } else {
          // V: Vt[(b*16+h)*128 + d][s], lg-paired uint4 (8 s-values)
          u16* O = (u16*)C2;
          int h = lc >> 7, d = lc & 127;
          int bb = row >> 11, s0 = row & 2047;
          unsigned w0 = (unsigned)f2bf(acc[mf][nf][0]) | ((unsigned)f2bf(acc[mf][nf][1]) << 16);
          unsigned w1 = (unsigned)f2bf(acc[mf][nf][2]) | ((unsigned)f2bf(acc[mf][nf][3]) << 16);
          unsigned w0p = __shfl_xor(w0, 16);
          unsigned w1p = __shfl_xor(w1, 16);
          if (!(lg & 1)) {
            *(uint4*)(O + ((size_t)((bb * 16 + h) * 128 + d) * 2048 + s0)) =
                make_uint4(w0, w1, w0p, w1p);
          }
        }
      }
    }
  }
}

// ======== causal flash attention: paired q-tiles, half-blocks, counted vmcnt (r10)
//          + in-register Q-RoPE (Q arrives un-roped; K is pre-roped) ========
__device__ __forceinline__ int kidx(int row, int colb) {  // Kl [64][128] u16
  return ((row << 8) + (colb ^ ((row & 7) << 4))) >> 1;
}
__device__ __forceinline__ int vidx(int row, int colb) {  // Vl [128][64] u16
  return ((row << 7) + (colb ^ ((row & 7) << 4))) >> 1;
}

__global__ __launch_bounds__(256, 2) void attn_kernel(const u16* __restrict__ Q,
                                                      const u16* __restrict__ K,
                                                      const u16* __restrict__ Vt,
                                                      const float2* __restrict__ ctab,
                                                      u16* __restrict__ ctx) {
  __shared__ u16 Kl[2][64 * 128];  // 32KB
  __shared__ u16 Vl[2][128 * 64];  // 32KB

  int tid = threadIdx.x;
  int lane = tid & 63, wave = tid >> 6;  // 4 waves
  int lr = lane & 15, lg = lane >> 4;
  int bh = blockIdx.x;
  int b = bh >> 4, h = bh & 15;
  int p = blockIdx.y;     // 0..7, longest (p=0) dispatched first
  int half = blockIdx.z;  // 0..1: 64-row half of each pair side
  int q0s = p * 128 + half * 64 + wave * 16;         // small-tile rows
  int q0b = (15 - p) * 128 + half * 64 + wave * 16;  // big-tile rows

  bf16x8 qf[2][4];
#pragma unroll
  for (int mf = 0; mf < 2; mf++) {
    int base = mf ? q0b : q0s;
    const u16* qbase = Q + (size_t)(b * S_LEN + base + lr) * DM + h * DKH;
#pragma unroll
    for (int ks = 0; ks < 4; ks++) qf[mf][ks] = *(const bf16x8*)(qbase + ks * 32 + lg * 8);
  }
  // in-register Q-RoPE: lane holds 8 consecutive d = ks*32+lg*8+j -> 4 (even,odd) pairs
#pragma unroll
  for (int mf = 0; mf < 2; mf++) {
    int base = mf ? q0b : q0s;
    const float2* ct = ctab + (size_t)(base + lr) * 64;
#pragma unroll
    for (int ks = 0; ks < 4; ks++) {
      bf16x8 q = qf[mf][ks];
      bf16x8 o;
      int i0 = ks * 16 + lg * 4;
#pragma unroll
      for (int pr = 0; pr < 4; pr++) {
        float2 cs = ct[i0 + pr];
        float a = (float)q[2 * pr], bb2 = (float)q[2 * pr + 1];
        o[2 * pr] = (__bf16)(a * cs.x - bb2 * cs.y);
        o[2 * pr + 1] = (__bf16)(a * cs.y + bb2 * cs.x);
      }
      qf[mf][ks] = o;
    }
  }

  f32x4 zero4 = {0.f, 0.f, 0.f, 0.f};
  f32x4 acc[2][8];
#pragma unroll
  for (int mf = 0; mf < 2; mf++)
#pragma unroll
    for (int f = 0; f < 8; f++) acc[mf][f] = zero4;
  float m_r[2], l_r[2];
#pragma unroll
  for (int mf = 0; mf < 2; mf++) { m_r[mf] = -3.0e38f; l_r[mf] = 0.f; }

  const float SL2E = 1.4426950408889634f * 0.08838834764831845f;
  const float RTHR = 64.0f;

  const u16* Kbh = K + (size_t)b * S_LEN * DM + h * DKH;
  const u16* Vbh = Vt + (size_t)(b * NH + h) * DKH * S_LEN;

  auto stage = [&](int buf, int kv0s) {
#pragma unroll
    for (int c = 0; c < 4; c++) {
      int ch = wave * 4 + c;  // 0..15
      int krow = ch * 4 + (lane >> 4);
      int kphi = (krow & 0x23) | ((krow & 0x10) >> 2) | ((krow & 0x0C) << 1);
      int kcb = ((((lane & 15) << 4) ^ ((krow & 7) << 4)) >> 1);
      async_copy16(&Kl[buf][ch * 512], Kbh + (size_t)(kv0s + kphi) * DM + kcb);
      int vrow = ch * 8 + (lane >> 3);
      int vcb = ((((lane & 7) << 4) ^ ((vrow & 7) << 4)) >> 1);
      async_copy16(&Vl[buf][ch * 512], Vbh + (size_t)vrow * S_LEN + kv0s + vcb);
    }
  };

  auto tileCompute = [&](int kv0, int bufIdx, auto nMfC) {
    constexpr int NMF = decltype(nMfC)::value;
    f32x4 sf[4][NMF];
#pragma unroll
    for (int kf = 0; kf < 4; kf++)
#pragma unroll
      for (int mi = 0; mi < NMF; mi++) sf[kf][mi] = zero4;
    __builtin_amdgcn_s_setprio(1);
#pragma unroll
    for (int ks = 0; ks < 4; ks++)
#pragma unroll
      for (int kf = 0; kf < 4; kf++) {
        bf16x8 kfrag = *(const bf16x8*)&Kl[bufIdx][kidx(kf * 16 + lr, ks * 64 + lg * 16)];
#pragma unroll
        for (int mi = 0; mi < NMF; mi++) {
          int mf = (NMF == 2) ? mi : 1;
          sf[kf][mi] = __builtin_amdgcn_mfma_f32_16x16x32_bf16(kfrag, qf[mf][ks], sf[kf][mi], 0, 0, 0);
        }
      }
    __builtin_amdgcn_s_setprio(0);

    float sv[NMF][4][4];
    float mx[NMF];
#pragma unroll
    for (int mi = 0; mi < NMF; mi++) {
      int mf = (NMF == 2) ? mi : 1;
      int base = mf ? q0b : q0s;
      int qg = base + lr;
      bool need_mask = (kv0 + 63 > base);
      mx[mi] = -3.0e38f;
#pragma unroll
      for (int kf = 0; kf < 4; kf++) {
        int kvb = kv0 + (kf >> 1) * 32 + (kf & 1) * 4 + lg * 8;
#pragma unroll
        for (int r = 0; r < 4; r++) {
          float x = sf[kf][mi][r];
          if (need_mask) x = (kvb + r <= qg) ? x : -3.0e38f;
          sv[mi][kf][r] = x;
          mx[mi] = fmaxf(mx[mi], x);
        }
      }
      mx[mi] = fmaxf(mx[mi], __shfl_xor(mx[mi], 16));
      mx[mi] = fmaxf(mx[mi], __shfl_xor(mx[mi], 32));
    }

    bool need = false;
#pragma unroll
    for (int mi = 0; mi < NMF; mi++) {
      int mf = (NMF == 2) ? mi : 1;
      need = need | (mx[mi] > m_r[mf] + RTHR);
    }
    if (__any(need)) {
      float scs[NMF];
#pragma unroll
      for (int mi = 0; mi < NMF; mi++) {
        int mf = (NMF == 2) ? mi : 1;
        float mnew = fmaxf(m_r[mf], mx[mi]);
        scs[mi] = __builtin_amdgcn_exp2f((m_r[mf] - mnew) * SL2E);
        m_r[mf] = mnew;
        l_r[mf] *= scs[mi];
      }
#pragma unroll
      for (int mi = 0; mi < NMF; mi++) {
        int mf = (NMF == 2) ? mi : 1;
#pragma unroll
        for (int r = 0; r < 4; r++) {
          float sa = __shfl(scs[mi], (lane & 0x30) | (lg * 4 + r));
#pragma unroll
          for (int f = 0; f < 8; f++) acc[mf][f][r] *= sa;
        }
      }
    }

    bf16x8 pf[NMF][2];
#pragma unroll
    for (int mi = 0; mi < NMF; mi++) {
      int mf = (NMF == 2) ? mi : 1;
      float rs = 0.f;
#pragma unroll
      for (int kf = 0; kf < 4; kf++)
#pragma unroll
        for (int r = 0; r < 4; r++) {
          float pv = __builtin_amdgcn_exp2f((sv[mi][kf][r] - m_r[mf]) * SL2E);
          sv[mi][kf][r] = pv;
          rs += pv;
        }
      rs += __shfl_xor(rs, 16);
      rs += __shfl_xor(rs, 32);
      l_r[mf] += rs;
#pragma unroll
      for (int ks2 = 0; ks2 < 2; ks2++) {
        bf16x8 t2;
#pragma unroll
        for (int r = 0; r < 4; r++) {
          t2[r] = (__bf16)sv[mi][2 * ks2][r];
          t2[4 + r] = (__bf16)sv[mi][2 * ks2 + 1][r];
        }
        pf[mi][ks2] = t2;
      }
    }

    __builtin_amdgcn_s_setprio(1);
#pragma unroll
    for (int ks2 = 0; ks2 < 2; ks2++)
#pragma unroll
      for (int f = 0; f < 8; f++) {
        bf16x8 vf = *(const bf16x8*)&Vl[bufIdx][vidx(f * 16 + lr, ks2 * 64 + lg * 16)];
#pragma unroll
        for (int mi = 0; mi < NMF; mi++) {
          int mf = (NMF == 2) ? mi : 1;
          acc[mf][f] = __builtin_amdgcn_mfma_f32_16x16x32_bf16(pf[mi][ks2], vf, acc[mf][f], 0, 0, 0);
        }
      }
    __builtin_amdgcn_s_setprio(0);
  };

  int ntB = 2 * (15 - p) + 2;  // shared K/V sweep length (big side)
  stage(0, 0);                 // 8 loads in flight
  int cur = 0;

  for (int t = 0; t < ntB; t++) {
    int kv0 = t * 64;
    if (t + 1 < ntB) {
      stage(cur ^ 1, (t + 1) * 64);                     // +8 loads (16 outstanding)
      asm volatile("s_waitcnt vmcnt(8)" ::: "memory");  // confirm prev tile's 8
    } else {
      asm volatile("s_waitcnt vmcnt(0)" ::: "memory");  // last tile: full drain
    }
    asm volatile("s_barrier" ::: "memory");             // raw: no vmcnt drain
    __builtin_amdgcn_sched_barrier(0);

    bool actS = (kv0 <= q0s + 15);  // wave-uniform
    bool actB = (kv0 <= q0b + 15);
    if (actS) tileCompute(kv0, cur, std::integral_constant<int, 2>{});
    else if (actB) tileCompute(kv0, cur, std::integral_constant<int, 1>{});

    asm volatile("s_barrier" ::: "memory");             // readers done before next stage
    cur ^= 1;
  }

#pragma unroll
  for (int mf = 0; mf < 2; mf++) {
    int base = mf ? q0b : q0s;
    float invl = 1.0f / l_r[mf];
#pragma unroll
    for (int r = 0; r < 4; r++) {
      float ia = __shfl(invl, (lane & 0x30) | (lg * 4 + r));
      int rowg = b * S_LEN + base + lg * 4 + r;
#pragma unroll
      for (int f = 0; f < 8; f++) {
        int colg = h * DKH + f * 16 + lr;
        ctx[(size_t)rowg * DM + colg] = f2bf(acc[mf][f][r] * ia);
      }
    }
  }
}

extern "C" void kernel_launch(void* const* d_in, const int* in_sizes, int n_in,
                              void* d_out, int out_size, void* d_ws, size_t ws_size,
                              hipStream_t stream) {
  const float* x = (const float*)d_in[0];
  const float* Wq = (const float*)d_in[1];
  const float* Wk = (const float*)d_in[2];
  const float* Wv = (const float*)d_in[3];
  const float* Wo = (const float*)d_in[4];
  float* out = (float*)d_out;

  char* ws = (char*)d_ws;
  size_t off = 0;
  auto alloc = [&](size_t bytes) -> char* {
    char* p = ws + off;
    off += (bytes + 255) & ~(size_t)255;
    return p;
  };
  u16* xb = (u16*)alloc((size_t)NROWS * DM * 2);     // reused as ctx
  u16* wqkv = (u16*)alloc((size_t)3 * DM * DM * 2);  // [Wq;Wk;Wv] rows
  u16* wob = (u16*)alloc((size_t)DM * DM * 2);
  u16* Qb = (u16*)alloc((size_t)NROWS * DM * 2);
  u16* Kb = (u16*)alloc((size_t)NROWS * DM * 2);
  u16* Vtb = (u16*)alloc((size_t)NROWS * DM * 2);
  float2* ctab = (float2*)alloc((size_t)S_LEN * 64 * 8);
  u16* ctx = xb;

  hipFuncSetAttribute((const void*)gemm256_kernel<3, 2>,
                      hipFuncAttributeMaxDynamicSharedMemorySize, 65536 + 2 * 192 * 128);
  hipFuncSetAttribute((const void*)gemm256_kernel<2, 0>,
                      hipFuncAttributeMaxDynamicSharedMemorySize, 65536 + 2 * 128 * 128);

  cast_all_kernel<<<2048, 256, 0, stream>>>(x, Wq, Wk, Wv, Wo, xb, wqkv, wob);
  rope_table_kernel<<<(S_LEN * 64 + 255) / 256, 256, 0, stream>>>(ctab);

  // fused QKV projection (column-cluster XCD swizzle): Q plain, K+RoPE, V->Vt
  gemm256_kernel<3, 2><<<dim3(3 * DM / 192, NROWS / 256), 512, 65536 + 2 * 192 * 128, stream>>>(
      xb, wqkv, Qb, Kb, Vtb, ctab, NROWS, 3 * DM, DM);

  // paired-tile attention (Q-RoPE in-register): 32 bh x 8 pairs x 2 halves = 512 blocks
  attn_kernel<<<dim3(NB * NH, 8, 2), 256, 0, stream>>>(Qb, Kb, Vtb, ctab, ctx);

  // output projection
  gemm256_kernel<2, 0><<<dim3(DM / 128, NROWS / 256), 512, 65536 + 2 * 128 * 128, stream>>>(
      ctx, wob, out, nullptr, nullptr, nullptr, NROWS, DM, DM);
}

// Round 13
// 259.255 us; speedup vs baseline: 1.0297x; 1.0297x over previous
//
#include <hip/hip_runtime.h>
#include <stdint.h>
#include <type_traits>

#define S_LEN 2048
#define DM 2048
#define NH 16
#define DKH 128
#define NB 2
#define NROWS (NB * S_LEN)  // 4096

typedef unsigned short u16;
typedef __attribute__((ext_vector_type(8))) __bf16 bf16x8;
typedef __attribute__((ext_vector_type(4))) float f32x4;

__device__ __forceinline__ float bf2f(u16 u) {
  union { unsigned u; float f; } v; v.u = ((unsigned)u) << 16; return v.f;
}
__device__ __forceinline__ u16 f2bf(float f) {
  union { float f; unsigned u; } v; v.f = f;
  unsigned r = v.u + 0x7FFFu + ((v.u >> 16) & 1u);
  return (u16)(r >> 16);
}

// async global->LDS, 16B per lane. lds = WAVE-UNIFORM chunk base (HW adds lane*16);
// g = PER-LANE global address.
__device__ __forceinline__ void async_copy16(void* lds, const void* g) {
  __builtin_amdgcn_global_load_lds(
      (const __attribute__((address_space(1))) unsigned int*)g,
      (__attribute__((address_space(3))) unsigned int*)lds, 16, 0, 0);
}

// ---------------- fused cast fp32 -> bf16 for all 5 inputs ----------------
__global__ void cast_all_kernel(const float* __restrict__ x, const float* __restrict__ wq,
                                const float* __restrict__ wk, const float* __restrict__ wv,
                                const float* __restrict__ wo, u16* __restrict__ xb,
                                u16* __restrict__ wqkv, u16* __restrict__ wob) {
  const int XN4 = NROWS * DM / 4;  // 2^21
  const int WN4 = DM * DM / 4;     // 2^20
  int total = XN4 + 4 * WN4;
  int stride = gridDim.x * blockDim.x;
  for (int i = blockIdx.x * blockDim.x + threadIdx.x; i < total; i += stride) {
    const float* s;
    u16* d;
    int j;
    if (i < XN4) {
      s = x; d = xb; j = i;
    } else {
      int k = i - XN4;
      int w = k >> 20;
      j = k & 0xFFFFF;
      if (w == 0) { s = wq; d = wqkv; }
      else if (w == 1) { s = wk; d = wqkv + (size_t)DM * DM; }
      else if (w == 2) { s = wv; d = wqkv + (size_t)2 * DM * DM; }
      else { s = wo; d = wob; }
    }
    float4 v = ((const float4*)s)[j];
    unsigned r0 = (unsigned)f2bf(v.x) | ((unsigned)f2bf(v.y) << 16);
    unsigned r1 = (unsigned)f2bf(v.z) | ((unsigned)f2bf(v.w) << 16);
    ((uint2*)d)[j] = make_uint2(r0, r1);
  }
}

// ---------------- RoPE cos/sin table: float2[S][64] ----------------
__global__ void rope_table_kernel(float2* __restrict__ ctab) {
  int idx = blockIdx.x * blockDim.x + threadIdx.x;
  if (idx >= S_LEN * 64) return;
  int s = idx >> 6, i = idx & 63;
  float inv = expf(-9.210340371976184f * (float)i * (1.0f / 64.0f));
  float fr = (float)s * inv;
  ctab[idx] = make_float2(cosf(fr), sinf(fr));
}

// ================= 256 x (64*NSEG) 8-phase GEMM (r8 K-loop, std XCD swizzle) =============
// EPI 0: f32 row-major out (Wo).
// EPI 2: QKV fused (NSEG=3): Q plain bf16 lane-paired stores (RoPE applied in attn);
//        K RoPE-in-epilogue lane-paired; V transposed Vt[(b*16+h)*128+d][s] lg-paired uint4.
template <int NSEG, int EPI>
__global__ __launch_bounds__(512, 1) void gemm256_kernel(const u16* __restrict__ A,
                                                         const u16* __restrict__ B,
                                                         void* __restrict__ C0,
                                                         void* __restrict__ C1,
                                                         void* __restrict__ C2,
                                                         const float2* __restrict__ ctab,
                                                         int M, int N, int Kd) {
  constexpr int BN = 64 * NSEG;
  constexpr int BSZ = BN * 128;  // bytes per B buffer
  constexpr int LDS_AE = 0, LDS_AO = 32768, LDS_BE = 65536, LDS_BO = 65536 + BSZ;

  extern __shared__ char smem[];
  u16* lds = (u16*)smem;

  int tid = threadIdx.x;
  int lane = tid & 63, wave = tid >> 6;
  int lr = lane & 15, lg = lane >> 4;
  int wm = wave >> 2, wn = wave & 3;

  int gx = gridDim.x, nwg = gx * gridDim.y;
  int bid = blockIdx.y * gx + blockIdx.x;
  int cpx = nwg >> 3;
  int swz = (bid & 7) * cpx + (bid >> 3);
  int tm = (swz / gx) * 256, tn = (swz % gx) * BN;

  int srow_in = lane >> 3;                             // 0..7
  int scolb = ((lane & 7) * 16) ^ ((lane >> 3) << 4);  // pre-swizzled src byte-col

  const u16* Arows = A + (size_t)tm * Kd;
  const u16* Brows = B + (size_t)tn * Kd;

  auto stageA = [&](int aBase, int h, int kt) {  // half h = 128 rows, 2 loads
#pragma unroll
    for (int l = 0; l < 2; l++) {
      int ch = h * 16 + l * 8 + wave;
      async_copy16(lds + ((aBase + ch * 1024) >> 1),
                   Arows + (size_t)(ch * 8 + srow_in) * Kd + kt * 64 + (scolb >> 1));
    }
  };
  auto stageB = [&](int bBase, int s, int kt) {  // seg s = 64 rows, 1 load
    int ch = s * 8 + wave;
    async_copy16(lds + ((bBase + ch * 1024) >> 1),
                 Brows + (size_t)(ch * 8 + srow_in) * Kd + kt * 64 + (scolb >> 1));
  };

  int acolb[2];
#pragma unroll
  for (int ks = 0; ks < 2; ks++) acolb[ks] = (ks * 64 + lg * 16) ^ ((lr & 7) << 4);
  int aBaseW = wm * 128 * 128;
  int brow_b = (wn * 16 * NSEG + lr) * 128;

  f32x4 zero4 = {0.f, 0.f, 0.f, 0.f};
  f32x4 acc[8][NSEG];
#pragma unroll
  for (int i = 0; i < 8; i++)
#pragma unroll
    for (int j = 0; j < NSEG; j++) acc[i][j] = zero4;

  bf16x8 bpre[NSEG][2];
  bf16x8 af[2][2];

  auto loadB = [&](int bBase) {
#pragma unroll
    for (int nf = 0; nf < NSEG; nf++)
#pragma unroll
      for (int ks = 0; ks < 2; ks++)
        bpre[nf][ks] = *(const bf16x8*)&lds[(bBase + brow_b + nf * 2048 + acolb[ks]) >> 1];
  };
  auto readA = [&](int aBase, int q) {
#pragma unroll
    for (int dm = 0; dm < 2; dm++)
#pragma unroll
      for (int ks = 0; ks < 2; ks++)
        af[dm][ks] = *(const bf16x8*)&lds[(aBase + aBaseW + (2 * q + dm) * 2048 + lr * 128 +
                                           acolb[ks]) >> 1];
  };
  auto mfmaC = [&](auto qc) {
    constexpr int Q = decltype(qc)::value;
    __builtin_amdgcn_s_setprio(1);
#pragma unroll
    for (int dm = 0; dm < 2; dm++)
#pragma unroll
      for (int nf = 0; nf < NSEG; nf++)
#pragma unroll
        for (int ks = 0; ks < 2; ks++)
          acc[2 * Q + dm][nf] = __builtin_amdgcn_mfma_f32_16x16x32_bf16(
              af[dm][ks], bpre[nf][ks], acc[2 * Q + dm][nf], 0, 0, 0);
    __builtin_amdgcn_s_setprio(0);
  };
  auto bar_pre = [&]() {
    __builtin_amdgcn_s_barrier();
    asm volatile("s_waitcnt lgkmcnt(0)" ::: "memory");
    __builtin_amdgcn_sched_barrier(0);
  };
  auto vm_wait = [&]() {
    if constexpr (NSEG == 3) asm volatile("s_waitcnt vmcnt(3)" ::: "memory");
    else asm volatile("s_waitcnt vmcnt(2)" ::: "memory");
  };

  int nk = Kd >> 6;
  int nIter = nk >> 1;

  stageA(LDS_AE, 0, 0);
  stageA(LDS_AE, 1, 0);
#pragma unroll
  for (int s = 0; s < NSEG; s++) stageB(LDS_BE, s, 0);
#pragma unroll
  for (int s = 0; s < NSEG; s++) stageB(LDS_BO, s, 1);
  vm_wait();
  __builtin_amdgcn_s_barrier();

  for (int i = 0; i < nIter; i++) {
    int tO = 2 * i + 1;
    int tE2 = 2 * i + 2; if (tE2 > nk - 1) tE2 = nk - 1;
    int tO2 = 2 * i + 3; if (tO2 > nk - 1) tO2 = nk - 1;

    // ---- ph0 ----
    loadB(LDS_BE); readA(LDS_AE, 0);
    stageA(LDS_AO, 0, tO);
    asm volatile("s_waitcnt lgkmcnt(8)" ::: "memory");
    bar_pre();
    mfmaC(std::integral_constant<int, 0>{});
    __builtin_amdgcn_s_barrier();
    // ---- ph1 ----
    readA(LDS_AE, 1);
    stageA(LDS_AO, 1, tO);
    bar_pre();
    mfmaC(std::integral_constant<int, 1>{});
    __builtin_amdgcn_s_barrier();
    // ---- ph2 ----
    readA(LDS_AE, 2);
    stageB(LDS_BE, 0, tE2);
    if constexpr (NSEG == 3) stageB(LDS_BE, 1, tE2);
    bar_pre();
    mfmaC(std::integral_constant<int, 2>{});
    __builtin_amdgcn_s_barrier();
    // ---- ph3 ----
    readA(LDS_AE, 3);
    stageB(LDS_BE, NSEG - 1, tE2);
    vm_wait();
    bar_pre();
    mfmaC(std::integral_constant<int, 3>{});
    __builtin_amdgcn_s_barrier();
    // ---- ph4 ----
    loadB(LDS_BO); readA(LDS_AO, 0);
    stageA(LDS_AE, 0, tE2);
    asm volatile("s_waitcnt lgkmcnt(8)" ::: "memory");
    bar_pre();
    mfmaC(std::integral_constant<int, 0>{});
    __builtin_amdgcn_s_barrier();
    // ---- ph5 ----
    readA(LDS_AO, 1);
    stageA(LDS_AE, 1, tE2);
    bar_pre();
    mfmaC(std::integral_constant<int, 1>{});
    __builtin_amdgcn_s_barrier();
    // ---- ph6 ----
    readA(LDS_AO, 2);
    stageB(LDS_BO, 0, tO2);
    if constexpr (NSEG == 3) stageB(LDS_BO, 1, tO2);
    bar_pre();
    mfmaC(std::integral_constant<int, 2>{});
    __builtin_amdgcn_s_barrier();
    // ---- ph7 ----
    readA(LDS_AO, 3);
    stageB(LDS_BO, NSEG - 1, tO2);
    vm_wait();
    bar_pre();
    mfmaC(std::integral_constant<int, 3>{});
    __builtin_amdgcn_s_barrier();
  }

  asm volatile("s_waitcnt vmcnt(0)" ::: "memory");

  // ---- epilogue ----
#pragma unroll
  for (int mf = 0; mf < 8; mf++) {
    int row = tm + wm * 128 + mf * 16 + lg * 4;
#pragma unroll
    for (int nf = 0; nf < NSEG; nf++) {
      int col = tn + wn * 16 * NSEG + nf * 16 + lr;
      if constexpr (EPI == 0) {
        float* O = (float*)C0;
#pragma unroll
        for (int r = 0; r < 4; r++) O[(size_t)(row + r) * N + col] = acc[mf][nf][r];
      } else {
        int mat = col >> 11, lc = col & 2047;  // frag-uniform (16-col frags)
        if (mat == 0) {
          // Q: plain bf16 lane-paired (RoPE applied inside attn)
          u16* O = (u16*)C0;
#pragma unroll
          for (int r = 0; r < 4; r++) {
            float a = acc[mf][nf][r];
            float b = __shfl_xor(a, 1);
            if (!(lr & 1)) {
              unsigned w = (unsigned)f2bf(a) | ((unsigned)f2bf(b) << 16);
              *(unsigned*)(O + (size_t)(row + r) * 2048 + lc) = w;
            }
          }
        } else if (mat == 1) {
          // K: RoPE in-epilogue, lane-paired stores
          u16* O = (u16*)C1;
          int d = lc & 127;
          bool odd = (d & 1) != 0;
          const float2* ct = ctab + (d >> 1);
#pragma unroll
          for (int r = 0; r < 4; r++) {
            float a = acc[mf][nf][r];
            float pp = __shfl_xor(a, 1);
            float2 cs = ct[((row + r) & (S_LEN - 1)) * 64];
            float o = odd ? (pp * cs.y + a * cs.x) : (a * cs.x - pp * cs.y);
            float ob = __shfl_xor(o, 1);
            if (!(lr & 1)) {
              unsigned w = (unsigned)f2bf(o) | ((unsigned)f2bf(ob) << 16);
              *(unsigned*)(O + (size_t)(row + r) * 2048 + lc) = w;
            }
          }
        } else {
          // V: Vt[(b*16+h)*128 + d][s], lg-paired uint4 (8 s-values)
          u16* O = (u16*)C2;
          int h = lc >> 7, d = lc & 127;
          int bb = row >> 11, s0 = row & 2047;
          unsigned w0 = (unsigned)f2bf(acc[mf][nf][0]) | ((unsigned)f2bf(acc[mf][nf][1]) << 16);
          unsigned w1 = (unsigned)f2bf(acc[mf][nf][2]) | ((unsigned)f2bf(acc[mf][nf][3]) << 16);
          unsigned w0p = __shfl_xor(w0, 16);
          unsigned w1p = __shfl_xor(w1, 16);
          if (!(lg & 1)) {
            *(uint4*)(O + ((size_t)((bb * 16 + h) * 128 + d) * 2048 + s0)) =
                make_uint4(w0, w1, w0p, w1p);
          }
        }
      }
    }
  }
}

// ======== causal flash attention: paired q-tiles, half-blocks, counted vmcnt,
// in-register Q-RoPE, MASK-templated tiles, deferred l-reduction ========
__device__ __forceinline__ int kidx(int row, int colb) {  // Kl [64][128] u16
  return ((row << 8) + (colb ^ ((row & 7) << 4))) >> 1;
}
__device__ __forceinline__ int vidx(int row, int colb) {  // Vl [128][64] u16
  return ((row << 7) + (colb ^ ((row & 7) << 4))) >> 1;
}

__global__ __launch_bounds__(256, 2) void attn_kernel(const u16* __restrict__ Q,
                                                      const u16* __restrict__ K,
                                                      const u16* __restrict__ Vt,
                                                      const float2* __restrict__ ctab,
                                                      u16* __restrict__ ctx) {
  __shared__ u16 Kl[2][64 * 128];  // 32KB
  __shared__ u16 Vl[2][128 * 64];  // 32KB

  int tid = threadIdx.x;
  int lane = tid & 63, wave = tid >> 6;  // 4 waves
  int lr = lane & 15, lg = lane >> 4;
  int bh = blockIdx.x;
  int b = bh >> 4, h = bh & 15;
  int p = blockIdx.y;     // 0..7, longest (p=0) dispatched first
  int half = blockIdx.z;  // 0..1: 64-row half of each pair side
  int q0s = p * 128 + half * 64 + wave * 16;         // small-tile rows
  int q0b = (15 - p) * 128 + half * 64 + wave * 16;  // big-tile rows

  bf16x8 qf[2][4];
#pragma unroll
  for (int mf = 0; mf < 2; mf++) {
    int base = mf ? q0b : q0s;
    const u16* qbase = Q + (size_t)(b * S_LEN + base + lr) * DM + h * DKH;
#pragma unroll
    for (int ks = 0; ks < 4; ks++) qf[mf][ks] = *(const bf16x8*)(qbase + ks * 32 + lg * 8);
  }
  // in-register Q-RoPE: lane holds 8 consecutive d = ks*32+lg*8+j -> 4 (even,odd) pairs
#pragma unroll
  for (int mf = 0; mf < 2; mf++) {
    int base = mf ? q0b : q0s;
    const float2* ct = ctab + (size_t)(base + lr) * 64;
#pragma unroll
    for (int ks = 0; ks < 4; ks++) {
      bf16x8 q = qf[mf][ks];
      bf16x8 o;
      int i0 = ks * 16 + lg * 4;
#pragma unroll
      for (int pr = 0; pr < 4; pr++) {
        float2 cs = ct[i0 + pr];
        float a = (float)q[2 * pr], bb2 = (float)q[2 * pr + 1];
        o[2 * pr] = (__bf16)(a * cs.x - bb2 * cs.y);
        o[2 * pr + 1] = (__bf16)(a * cs.y + bb2 * cs.x);
      }
      qf[mf][ks] = o;
    }
  }

  f32x4 zero4 = {0.f, 0.f, 0.f, 0.f};
  f32x4 acc[2][8];
#pragma unroll
  for (int mf = 0; mf < 2; mf++)
#pragma unroll
    for (int f = 0; f < 8; f++) acc[mf][f] = zero4;
  float m_r[2], l_r[2];  // l_r = PER-LANE partial row-sum (reduced at epilogue)
#pragma unroll
  for (int mf = 0; mf < 2; mf++) { m_r[mf] = -3.0e38f; l_r[mf] = 0.f; }

  const float SL2E = 1.4426950408889634f * 0.08838834764831845f;
  const float RTHR = 64.0f;

  const u16* Kbh = K + (size_t)b * S_LEN * DM + h * DKH;
  const u16* Vbh = Vt + (size_t)(b * NH + h) * DKH * S_LEN;

  auto stage = [&](int buf, int kv0s) {
#pragma unroll
    for (int c = 0; c < 4; c++) {
      int ch = wave * 4 + c;  // 0..15
      int krow = ch * 4 + (lane >> 4);
      int kphi = (krow & 0x23) | ((krow & 0x10) >> 2) | ((krow & 0x0C) << 1);
      int kcb = ((((lane & 15) << 4) ^ ((krow & 7) << 4)) >> 1);
      async_copy16(&Kl[buf][ch * 512], Kbh + (size_t)(kv0s + kphi) * DM + kcb);
      int vrow = ch * 8 + (lane >> 3);
      int vcb = ((((lane & 7) << 4) ^ ((vrow & 7) << 4)) >> 1);
      async_copy16(&Vl[buf][ch * 512], Vbh + (size_t)vrow * S_LEN + kv0s + vcb);
    }
  };

  // NMF: sides computed (2 = small+big, 1 = big only). MASKED: apply causal mask.
  auto tileCompute = [&](int kv0, int bufIdx, auto nMfC, auto maskC) {
    constexpr int NMF = decltype(nMfC)::value;
    constexpr int MASKED = decltype(maskC)::value;
    f32x4 sf[4][NMF];
#pragma unroll
    for (int kf = 0; kf < 4; kf++)
#pragma unroll
      for (int mi = 0; mi < NMF; mi++) sf[kf][mi] = zero4;
    __builtin_amdgcn_s_setprio(1);
#pragma unroll
    for (int ks = 0; ks < 4; ks++)
#pragma unroll
      for (int kf = 0; kf < 4; kf++) {
        bf16x8 kfrag = *(const bf16x8*)&Kl[bufIdx][kidx(kf * 16 + lr, ks * 64 + lg * 16)];
#pragma unroll
        for (int mi = 0; mi < NMF; mi++) {
          int mf = (NMF == 2) ? mi : 1;
          sf[kf][mi] = __builtin_amdgcn_mfma_f32_16x16x32_bf16(kfrag, qf[mf][ks], sf[kf][mi], 0, 0, 0);
        }
      }
    __builtin_amdgcn_s_setprio(0);

    float sv[NMF][4][4];
    float mx[NMF];
#pragma unroll
    for (int mi = 0; mi < NMF; mi++) {
      int mf = (NMF == 2) ? mi : 1;
      int base = mf ? q0b : q0s;
      int qg = base + lr;
      mx[mi] = -3.0e38f;
#pragma unroll
      for (int kf = 0; kf < 4; kf++) {
        int kvb = kv0 + (kf >> 1) * 32 + (kf & 1) * 4 + lg * 8;
#pragma unroll
        for (int r = 0; r < 4; r++) {
          float x = sf[kf][mi][r];
          if constexpr (MASKED) {
            bool need_mask = (kv0 + 63 > base);
            if (need_mask) x = (kvb + r <= qg) ? x : -3.0e38f;
          }
          sv[mi][kf][r] = x;
          mx[mi] = fmaxf(mx[mi], x);
        }
      }
      mx[mi] = fmaxf(mx[mi], __shfl_xor(mx[mi], 16));
      mx[mi] = fmaxf(mx[mi], __shfl_xor(mx[mi], 32));
    }

    bool need = false;
#pragma unroll
    for (int mi = 0; mi < NMF; mi++) {
      int mf = (NMF == 2) ? mi : 1;
      need = need | (mx[mi] > m_r[mf] + RTHR);
    }
    if (__any(need)) {
      float scs[NMF];
#pragma unroll
      for (int mi = 0; mi < NMF; mi++) {
        int mf = (NMF == 2) ? mi : 1;
        float mnew = fmaxf(m_r[mf], mx[mi]);
        scs[mi] = __builtin_amdgcn_exp2f((m_r[mf] - mnew) * SL2E);
        m_r[mf] = mnew;
        l_r[mf] *= scs[mi];  // per-lane partial scales uniformly (scs lane-uniform)
      }
#pragma unroll
      for (int mi = 0; mi < NMF; mi++) {
        int mf = (NMF == 2) ? mi : 1;
#pragma unroll
        for (int r = 0; r < 4; r++) {
          float sa = __shfl(scs[mi], (lane & 0x30) | (lg * 4 + r));
#pragma unroll
          for (int f = 0; f < 8; f++) acc[mf][f][r] *= sa;
        }
      }
    }

    bf16x8 pf[NMF][2];
#pragma unroll
    for (int mi = 0; mi < NMF; mi++) {
      int mf = (NMF == 2) ? mi : 1;
      float rs = 0.f;
#pragma unroll
      for (int kf = 0; kf < 4; kf++)
#pragma unroll
        for (int r = 0; r < 4; r++) {
          float pv = __builtin_amdgcn_exp2f((sv[mi][kf][r] - m_r[mf]) * SL2E);
          sv[mi][kf][r] = pv;
          rs += pv;
        }
      l_r[mf] += rs;  // deferred: cross-lane reduce moved to epilogue
#pragma unroll
      for (int ks2 = 0; ks2 < 2; ks2++) {
        bf16x8 t2;
#pragma unroll
        for (int r = 0; r < 4; r++) {
          t2[r] = (__bf16)sv[mi][2 * ks2][r];
          t2[4 + r] = (__bf16)sv[mi][2 * ks2 + 1][r];
        }
        pf[mi][ks2] = t2;
      }
    }

    __builtin_amdgcn_s_setprio(1);
#pragma unroll
    for (int ks2 = 0; ks2 < 2; ks2++)
#pragma unroll
      for (int f = 0; f < 8; f++) {
        bf16x8 vf = *(const bf16x8*)&Vl[bufIdx][vidx(f * 16 + lr, ks2 * 64 + lg * 16)];
#pragma unroll
        for (int mi = 0; mi < NMF; mi++) {
          int mf = (NMF == 2) ? mi : 1;
          acc[mf][f] = __builtin_amdgcn_mfma_f32_16x16x32_bf16(pf[mi][ks2], vf, acc[mf][f], 0, 0, 0);
        }
      }
    __builtin_amdgcn_s_setprio(0);
  };

  int ntB = 2 * (15 - p) + 2;  // shared K/V sweep length (big side)
  stage(0, 0);                 // 8 loads in flight
  int cur = 0;

  for (int t = 0; t < ntB; t++) {
    int kv0 = t * 64;
    if (t + 1 < ntB) {
      stage(cur ^ 1, (t + 1) * 64);                     // +8 loads (16 outstanding)
      asm volatile("s_waitcnt vmcnt(8)" ::: "memory");  // confirm prev tile's 8
    } else {
      asm volatile("s_waitcnt vmcnt(0)" ::: "memory");  // last tile: full drain
    }
    asm volatile("s_barrier" ::: "memory");             // raw: no vmcnt drain
    __builtin_amdgcn_sched_barrier(0);

    bool actS = (kv0 <= q0s + 15);  // wave-uniform
    bool actB = (kv0 <= q0b + 15);
    bool mS = (kv0 + 63 > q0s);
    bool mB = (kv0 + 63 > q0b);
    if (actS) {
      if (mS | mB) tileCompute(kv0, cur, std::integral_constant<int, 2>{},
                               std::integral_constant<int, 1>{});
      else tileCompute(kv0, cur, std::integral_constant<int, 2>{},
                       std::integral_constant<int, 0>{});
    } else if (actB) {
      if (mB) tileCompute(kv0, cur, std::integral_constant<int, 1>{},
                          std::integral_constant<int, 1>{});
      else tileCompute(kv0, cur, std::integral_constant<int, 1>{},
                       std::integral_constant<int, 0>{});
    }

    asm volatile("s_barrier" ::: "memory");             // readers done before next stage
    cur ^= 1;
  }

#pragma unroll
  for (int mf = 0; mf < 2; mf++) {
    int base = mf ? q0b : q0s;
    float lsum = l_r[mf];
    lsum += __shfl_xor(lsum, 16);
    lsum += __shfl_xor(lsum, 32);
    float invl = 1.0f / lsum;
#pragma unroll
    for (int r = 0; r < 4; r++) {
      float ia = __shfl(invl, (lane & 0x30) | (lg * 4 + r));
      int rowg = b * S_LEN + base + lg * 4 + r;
#pragma unroll
      for (int f = 0; f < 8; f++) {
        int colg = h * DKH + f * 16 + lr;
        ctx[(size_t)rowg * DM + colg] = f2bf(acc[mf][f][r] * ia);
      }
    }
  }
}

extern "C" void kernel_launch(void* const* d_in, const int* in_sizes, int n_in,
                              void* d_out, int out_size, void* d_ws, size_t ws_size,
                              hipStream_t stream) {
  const float* x = (const float*)d_in[0];
  const float* Wq = (const float*)d_in[1];
  const float* Wk = (const float*)d_in[2];
  const float* Wv = (const float*)d_in[3];
  const float* Wo = (const float*)d_in[4];
  float* out = (float*)d_out;

  char* ws = (char*)d_ws;
  size_t off = 0;
  auto alloc = [&](size_t bytes) -> char* {
    char* p = ws + off;
    off += (bytes + 255) & ~(size_t)255;
    return p;
  };
  u16* xb = (u16*)alloc((size_t)NROWS * DM * 2);     // reused as ctx
  u16* wqkv = (u16*)alloc((size_t)3 * DM * DM * 2);  // [Wq;Wk;Wv] rows
  u16* wob = (u16*)alloc((size_t)DM * DM * 2);
  u16* Qb = (u16*)alloc((size_t)NROWS * DM * 2);
  u16* Kb = (u16*)alloc((size_t)NROWS * DM * 2);
  u16* Vtb = (u16*)alloc((size_t)NROWS * DM * 2);
  float2* ctab = (float2*)alloc((size_t)S_LEN * 64 * 8);
  u16* ctx = xb;

  hipFuncSetAttribute((const void*)gemm256_kernel<3, 2>,
                      hipFuncAttributeMaxDynamicSharedMemorySize, 65536 + 2 * 192 * 128);
  hipFuncSetAttribute((const void*)gemm256_kernel<2, 0>,
                      hipFuncAttributeMaxDynamicSharedMemorySize, 65536 + 2 * 128 * 128);

  cast_all_kernel<<<2048, 256, 0, stream>>>(x, Wq, Wk, Wv, Wo, xb, wqkv, wob);
  rope_table_kernel<<<(S_LEN * 64 + 255) / 256, 256, 0, stream>>>(ctab);

  // fused QKV projection (std swizzle): Q plain, K+RoPE, V->Vt
  gemm256_kernel<3, 2><<<dim3(3 * DM / 192, NROWS / 256), 512, 65536 + 2 * 192 * 128, stream>>>(
      xb, wqkv, Qb, Kb, Vtb, ctab, NROWS, 3 * DM, DM);

  // paired-tile attention (Q-RoPE in-register): 32 bh x 8 pairs x 2 halves = 512 blocks
  attn_kernel<<<dim3(NB * NH, 8, 2), 256, 0, stream>>>(Qb, Kb, Vtb, ctab, ctx);

  // output projection
  gemm256_kernel<2, 0><<<dim3(DM / 128, NROWS / 256), 512, 65536 + 2 * 128 * 128, stream>>>(
      ctx, wob, out, nullptr, nullptr, nullptr, NROWS, DM, DM);
}

// Round 14
// 234.158 us; speedup vs baseline: 1.1400x; 1.1072x over previous
//
#include <hip/hip_runtime.h>
#include <stdint.h>
#include <type_traits>

#define S_LEN 2048
#define DM 2048
#define NH 16
#define DKH 128
#define NB 2
#define NROWS (NB * S_LEN)  // 4096

typedef unsigned short u16;
typedef __attribute__((ext_vector_type(8))) __bf16 bf16x8;
typedef __attribute__((ext_vector_type(4))) float f32x4;

__device__ __forceinline__ float bf2f(u16 u) {
  union { unsigned u; float f; } v; v.u = ((unsigned)u) << 16; return v.f;
}
__device__ __forceinline__ u16 f2bf(float f) {
  union { float f; unsigned u; } v; v.f = f;
  unsigned r = v.u + 0x7FFFu + ((v.u >> 16) & 1u);
  return (u16)(r >> 16);
}

// async global->LDS, 16B per lane. lds = WAVE-UNIFORM chunk base (HW adds lane*16);
// g = PER-LANE global address.
__device__ __forceinline__ void async_copy16(void* lds, const void* g) {
  __builtin_amdgcn_global_load_lds(
      (const __attribute__((address_space(1))) unsigned int*)g,
      (__attribute__((address_space(3))) unsigned int*)lds, 16, 0, 0);
}

// ---------------- fused cast fp32 -> bf16 for all 5 inputs ----------------
__global__ void cast_all_kernel(const float* __restrict__ x, const float* __restrict__ wq,
                                const float* __restrict__ wk, const float* __restrict__ wv,
                                const float* __restrict__ wo, u16* __restrict__ xb,
                                u16* __restrict__ wqkv, u16* __restrict__ wob) {
  const int XN4 = NROWS * DM / 4;  // 2^21
  const int WN4 = DM * DM / 4;     // 2^20
  int total = XN4 + 4 * WN4;
  int stride = gridDim.x * blockDim.x;
  for (int i = blockIdx.x * blockDim.x + threadIdx.x; i < total; i += stride) {
    const float* s;
    u16* d;
    int j;
    if (i < XN4) {
      s = x; d = xb; j = i;
    } else {
      int k = i - XN4;
      int w = k >> 20;
      j = k & 0xFFFFF;
      if (w == 0) { s = wq; d = wqkv; }
      else if (w == 1) { s = wk; d = wqkv + (size_t)DM * DM; }
      else if (w == 2) { s = wv; d = wqkv + (size_t)2 * DM * DM; }
      else { s = wo; d = wob; }
    }
    float4 v = ((const float4*)s)[j];
    unsigned r0 = (unsigned)f2bf(v.x) | ((unsigned)f2bf(v.y) << 16);
    unsigned r1 = (unsigned)f2bf(v.z) | ((unsigned)f2bf(v.w) << 16);
    ((uint2*)d)[j] = make_uint2(r0, r1);
  }
}

// ---------------- RoPE cos/sin table: float2[S][64] ----------------
__global__ void rope_table_kernel(float2* __restrict__ ctab) {
  int idx = blockIdx.x * blockDim.x + threadIdx.x;
  if (idx >= S_LEN * 64) return;
  int s = idx >> 6, i = idx & 63;
  float inv = expf(-9.210340371976184f * (float)i * (1.0f / 64.0f));
  float fr = (float)s * inv;
  ctab[idx] = make_float2(cosf(fr), sinf(fr));
}

// ================= 256 x (64*NSEG) 8-phase GEMM (r8/r10 known-best, verbatim) =============
template <int NSEG, int EPI>
__global__ __launch_bounds__(512, 1) void gemm256_kernel(const u16* __restrict__ A,
                                                         const u16* __restrict__ B,
                                                         void* __restrict__ C0,
                                                         void* __restrict__ C1,
                                                         void* __restrict__ C2,
                                                         const float2* __restrict__ ctab,
                                                         int M, int N, int Kd) {
  constexpr int BN = 64 * NSEG;
  constexpr int BSZ = BN * 128;  // bytes per B buffer
  constexpr int LDS_AE = 0, LDS_AO = 32768, LDS_BE = 65536, LDS_BO = 65536 + BSZ;

  extern __shared__ char smem[];
  u16* lds = (u16*)smem;

  int tid = threadIdx.x;
  int lane = tid & 63, wave = tid >> 6;
  int lr = lane & 15, lg = lane >> 4;
  int wm = wave >> 2, wn = wave & 3;

  int gx = gridDim.x, nwg = gx * gridDim.y;
  int bid = blockIdx.y * gx + blockIdx.x;
  int cpx = nwg >> 3;
  int swz = (bid & 7) * cpx + (bid >> 3);
  int tm = (swz / gx) * 256, tn = (swz % gx) * BN;

  int srow_in = lane >> 3;                             // 0..7
  int scolb = ((lane & 7) * 16) ^ ((lane >> 3) << 4);  // pre-swizzled src byte-col

  const u16* Arows = A + (size_t)tm * Kd;
  const u16* Brows = B + (size_t)tn * Kd;

  auto stageA = [&](int aBase, int h, int kt) {  // half h = 128 rows, 2 loads
#pragma unroll
    for (int l = 0; l < 2; l++) {
      int ch = h * 16 + l * 8 + wave;
      async_copy16(lds + ((aBase + ch * 1024) >> 1),
                   Arows + (size_t)(ch * 8 + srow_in) * Kd + kt * 64 + (scolb >> 1));
    }
  };
  auto stageB = [&](int bBase, int s, int kt) {  // seg s = 64 rows, 1 load
    int ch = s * 8 + wave;
    async_copy16(lds + ((bBase + ch * 1024) >> 1),
                 Brows + (size_t)(ch * 8 + srow_in) * Kd + kt * 64 + (scolb >> 1));
  };

  int acolb[2];
#pragma unroll
  for (int ks = 0; ks < 2; ks++) acolb[ks] = (ks * 64 + lg * 16) ^ ((lr & 7) << 4);
  int aBaseW = wm * 128 * 128;
  int brow_b = (wn * 16 * NSEG + lr) * 128;

  f32x4 zero4 = {0.f, 0.f, 0.f, 0.f};
  f32x4 acc[8][NSEG];
#pragma unroll
  for (int i = 0; i < 8; i++)
#pragma unroll
    for (int j = 0; j < NSEG; j++) acc[i][j] = zero4;

  bf16x8 bpre[NSEG][2];
  bf16x8 af[2][2];

  auto loadB = [&](int bBase) {
#pragma unroll
    for (int nf = 0; nf < NSEG; nf++)
#pragma unroll
      for (int ks = 0; ks < 2; ks++)
        bpre[nf][ks] = *(const bf16x8*)&lds[(bBase + brow_b + nf * 2048 + acolb[ks]) >> 1];
  };
  auto readA = [&](int aBase, int q) {
#pragma unroll
    for (int dm = 0; dm < 2; dm++)
#pragma unroll
      for (int ks = 0; ks < 2; ks++)
        af[dm][ks] = *(const bf16x8*)&lds[(aBase + aBaseW + (2 * q + dm) * 2048 + lr * 128 +
                                           acolb[ks]) >> 1];
  };
  auto mfmaC = [&](auto qc) {
    constexpr int Q = decltype(qc)::value;
    __builtin_amdgcn_s_setprio(1);
#pragma unroll
    for (int dm = 0; dm < 2; dm++)
#pragma unroll
      for (int nf = 0; nf < NSEG; nf++)
#pragma unroll
        for (int ks = 0; ks < 2; ks++)
          acc[2 * Q + dm][nf] = __builtin_amdgcn_mfma_f32_16x16x32_bf16(
              af[dm][ks], bpre[nf][ks], acc[2 * Q + dm][nf], 0, 0, 0);
    __builtin_amdgcn_s_setprio(0);
  };
  auto bar_pre = [&]() {
    __builtin_amdgcn_s_barrier();
    asm volatile("s_waitcnt lgkmcnt(0)" ::: "memory");
    __builtin_amdgcn_sched_barrier(0);
  };
  auto vm_wait = [&]() {
    if constexpr (NSEG == 3) asm volatile("s_waitcnt vmcnt(3)" ::: "memory");
    else asm volatile("s_waitcnt vmcnt(2)" ::: "memory");
  };

  int nk = Kd >> 6;
  int nIter = nk >> 1;

  stageA(LDS_AE, 0, 0);
  stageA(LDS_AE, 1, 0);
#pragma unroll
  for (int s = 0; s < NSEG; s++) stageB(LDS_BE, s, 0);
#pragma unroll
  for (int s = 0; s < NSEG; s++) stageB(LDS_BO, s, 1);
  vm_wait();
  __builtin_amdgcn_s_barrier();

  for (int i = 0; i < nIter; i++) {
    int tO = 2 * i + 1;
    int tE2 = 2 * i + 2; if (tE2 > nk - 1) tE2 = nk - 1;
    int tO2 = 2 * i + 3; if (tO2 > nk - 1) tO2 = nk - 1;

    // ---- ph0 ----
    loadB(LDS_BE); readA(LDS_AE, 0);
    stageA(LDS_AO, 0, tO);
    asm volatile("s_waitcnt lgkmcnt(8)" ::: "memory");
    bar_pre();
    mfmaC(std::integral_constant<int, 0>{});
    __builtin_amdgcn_s_barrier();
    // ---- ph1 ----
    readA(LDS_AE, 1);
    stageA(LDS_AO, 1, tO);
    bar_pre();
    mfmaC(std::integral_constant<int, 1>{});
    __builtin_amdgcn_s_barrier();
    // ---- ph2 ----
    readA(LDS_AE, 2);
    stageB(LDS_BE, 0, tE2);
    if constexpr (NSEG == 3) stageB(LDS_BE, 1, tE2);
    bar_pre();
    mfmaC(std::integral_constant<int, 2>{});
    __builtin_amdgcn_s_barrier();
    // ---- ph3 ----
    readA(LDS_AE, 3);
    stageB(LDS_BE, NSEG - 1, tE2);
    vm_wait();
    bar_pre();
    mfmaC(std::integral_constant<int, 3>{});
    __builtin_amdgcn_s_barrier();
    // ---- ph4 ----
    loadB(LDS_BO); readA(LDS_AO, 0);
    stageA(LDS_AE, 0, tE2);
    asm volatile("s_waitcnt lgkmcnt(8)" ::: "memory");
    bar_pre();
    mfmaC(std::integral_constant<int, 0>{});
    __builtin_amdgcn_s_barrier();
    // ---- ph5 ----
    readA(LDS_AO, 1);
    stageA(LDS_AE, 1, tE2);
    bar_pre();
    mfmaC(std::integral_constant<int, 1>{});
    __builtin_amdgcn_s_barrier();
    // ---- ph6 ----
    readA(LDS_AO, 2);
    stageB(LDS_BO, 0, tO2);
    if constexpr (NSEG == 3) stageB(LDS_BO, 1, tO2);
    bar_pre();
    mfmaC(std::integral_constant<int, 2>{});
    __builtin_amdgcn_s_barrier();
    // ---- ph7 ----
    readA(LDS_AO, 3);
    stageB(LDS_BO, NSEG - 1, tO2);
    vm_wait();
    bar_pre();
    mfmaC(std::integral_constant<int, 3>{});
    __builtin_amdgcn_s_barrier();
  }

  asm volatile("s_waitcnt vmcnt(0)" ::: "memory");

#pragma unroll
  for (int mf = 0; mf < 8; mf++) {
    int row = tm + wm * 128 + mf * 16 + lg * 4;
#pragma unroll
    for (int nf = 0; nf < NSEG; nf++) {
      int col = tn + wn * 16 * NSEG + nf * 16 + lr;
      if constexpr (EPI == 0) {
        float* O = (float*)C0;
#pragma unroll
        for (int r = 0; r < 4; r++) O[(size_t)(row + r) * N + col] = acc[mf][nf][r];
      } else {
        int mat = col >> 11, lc = col & 2047;
        if (mat < 2) {
          u16* O = (mat == 0) ? (u16*)C0 : (u16*)C1;
          int d = lc & 127;
          bool odd = (d & 1) != 0;
          const float2* ct = ctab + (d >> 1);
#pragma unroll
          for (int r = 0; r < 4; r++) {
            float a = acc[mf][nf][r];
            float pp = __shfl_xor(a, 1);
            int sIdx = (row + r) & (S_LEN - 1);
            float2 cs = ct[sIdx * 64];
            float o = odd ? (pp * cs.y + a * cs.x) : (a * cs.x - pp * cs.y);
            O[(size_t)(row + r) * 2048 + lc] = f2bf(o);
          }
        } else {
          u16* O = (u16*)C2;  // Vt[(b*16+h)*128 + d][s]
          int h = lc >> 7, d = lc & 127;
          int bb = row >> 11, s0 = row & 2047;
          unsigned w0 = (unsigned)f2bf(acc[mf][nf][0]) | ((unsigned)f2bf(acc[mf][nf][1]) << 16);
          unsigned w1 = (unsigned)f2bf(acc[mf][nf][2]) | ((unsigned)f2bf(acc[mf][nf][3]) << 16);
          *(uint2*)(O + ((size_t)((bb * 16 + h) * 128 + d) * 2048 + s0)) = make_uint2(w0, w1);
        }
      }
    }
  }
}

// ======== causal flash attention: paired q-tiles, half-blocks, counted vmcnt (r10)
//          + MASK-templated tiles + deferred l-reduction ========
__device__ __forceinline__ int kidx(int row, int colb) {  // Kl [64][128] u16
  return ((row << 8) + (colb ^ ((row & 7) << 4))) >> 1;
}
__device__ __forceinline__ int vidx(int row, int colb) {  // Vl [128][64] u16
  return ((row << 7) + (colb ^ ((row & 7) << 4))) >> 1;
}

__global__ __launch_bounds__(256, 2) void attn_kernel(const u16* __restrict__ Q,
                                                      const u16* __restrict__ K,
                                                      const u16* __restrict__ Vt,
                                                      u16* __restrict__ ctx) {
  __shared__ u16 Kl[2][64 * 128];  // 32KB
  __shared__ u16 Vl[2][128 * 64];  // 32KB

  int tid = threadIdx.x;
  int lane = tid & 63, wave = tid >> 6;  // 4 waves
  int lr = lane & 15, lg = lane >> 4;
  int bh = blockIdx.x;
  int b = bh >> 4, h = bh & 15;
  int p = blockIdx.y;     // 0..7, longest (p=0) dispatched first
  int half = blockIdx.z;  // 0..1: 64-row half of each pair side
  int q0s = p * 128 + half * 64 + wave * 16;         // small-tile rows
  int q0b = (15 - p) * 128 + half * 64 + wave * 16;  // big-tile rows

  bf16x8 qf[2][4];
#pragma unroll
  for (int mf = 0; mf < 2; mf++) {
    int base = mf ? q0b : q0s;
    const u16* qbase = Q + (size_t)(b * S_LEN + base + lr) * DM + h * DKH;
#pragma unroll
    for (int ks = 0; ks < 4; ks++) qf[mf][ks] = *(const bf16x8*)(qbase + ks * 32 + lg * 8);
  }

  f32x4 zero4 = {0.f, 0.f, 0.f, 0.f};
  f32x4 acc[2][8];
#pragma unroll
  for (int mf = 0; mf < 2; mf++)
#pragma unroll
    for (int f = 0; f < 8; f++) acc[mf][f] = zero4;
  float m_r[2], l_r[2];  // l_r = PER-LANE partial row-sum (reduced at epilogue)
#pragma unroll
  for (int mf = 0; mf < 2; mf++) { m_r[mf] = -3.0e38f; l_r[mf] = 0.f; }

  const float SL2E = 1.4426950408889634f * 0.08838834764831845f;
  const float RTHR = 64.0f;

  const u16* Kbh = K + (size_t)b * S_LEN * DM + h * DKH;
  const u16* Vbh = Vt + (size_t)(b * NH + h) * DKH * S_LEN;

  auto stage = [&](int buf, int kv0s) {
#pragma unroll
    for (int c = 0; c < 4; c++) {
      int ch = wave * 4 + c;  // 0..15
      int krow = ch * 4 + (lane >> 4);
      int kphi = (krow & 0x23) | ((krow & 0x10) >> 2) | ((krow & 0x0C) << 1);
      int kcb = ((((lane & 15) << 4) ^ ((krow & 7) << 4)) >> 1);
      async_copy16(&Kl[buf][ch * 512], Kbh + (size_t)(kv0s + kphi) * DM + kcb);
      int vrow = ch * 8 + (lane >> 3);
      int vcb = ((((lane & 7) << 4) ^ ((vrow & 7) << 4)) >> 1);
      async_copy16(&Vl[buf][ch * 512], Vbh + (size_t)vrow * S_LEN + kv0s + vcb);
    }
  };

  // NMF: sides computed (2 = small+big, 1 = big only). MASKED: apply causal mask.
  auto tileCompute = [&](int kv0, int bufIdx, auto nMfC, auto maskC) {
    constexpr int NMF = decltype(nMfC)::value;
    constexpr int MASKED = decltype(maskC)::value;
    f32x4 sf[4][NMF];
#pragma unroll
    for (int kf = 0; kf < 4; kf++)
#pragma unroll
      for (int mi = 0; mi < NMF; mi++) sf[kf][mi] = zero4;
    __builtin_amdgcn_s_setprio(1);
#pragma unroll
    for (int ks = 0; ks < 4; ks++)
#pragma unroll
      for (int kf = 0; kf < 4; kf++) {
        bf16x8 kfrag = *(const bf16x8*)&Kl[bufIdx][kidx(kf * 16 + lr, ks * 64 + lg * 16)];
#pragma unroll
        for (int mi = 0; mi < NMF; mi++) {
          int mf = (NMF == 2) ? mi : 1;
          sf[kf][mi] = __builtin_amdgcn_mfma_f32_16x16x32_bf16(kfrag, qf[mf][ks], sf[kf][mi], 0, 0, 0);
        }
      }
    __builtin_amdgcn_s_setprio(0);

    float sv[NMF][4][4];
    float mx[NMF];
#pragma unroll
    for (int mi = 0; mi < NMF; mi++) {
      int mf = (NMF == 2) ? mi : 1;
      int base = mf ? q0b : q0s;
      int qg = base + lr;
      mx[mi] = -3.0e38f;
#pragma unroll
      for (int kf = 0; kf < 4; kf++) {
        int kvb = kv0 + (kf >> 1) * 32 + (kf & 1) * 4 + lg * 8;
#pragma unroll
        for (int r = 0; r < 4; r++) {
          float x = sf[kf][mi][r];
          if constexpr (MASKED) {
            bool need_mask = (kv0 + 63 > base);
            if (need_mask) x = (kvb + r <= qg) ? x : -3.0e38f;
          }
          sv[mi][kf][r] = x;
          mx[mi] = fmaxf(mx[mi], x);
        }
      }
      mx[mi] = fmaxf(mx[mi], __shfl_xor(mx[mi], 16));
      mx[mi] = fmaxf(mx[mi], __shfl_xor(mx[mi], 32));
    }

    bool need = false;
#pragma unroll
    for (int mi = 0; mi < NMF; mi++) {
      int mf = (NMF == 2) ? mi : 1;
      need = need | (mx[mi] > m_r[mf] + RTHR);
    }
    if (__any(need)) {
      float scs[NMF];
#pragma unroll
      for (int mi = 0; mi < NMF; mi++) {
        int mf = (NMF == 2) ? mi : 1;
        float mnew = fmaxf(m_r[mf], mx[mi]);
        scs[mi] = __builtin_amdgcn_exp2f((m_r[mf] - mnew) * SL2E);
        m_r[mf] = mnew;
        l_r[mf] *= scs[mi];  // lane-uniform factor -> per-lane partial stays consistent
      }
#pragma unroll
      for (int mi = 0; mi < NMF; mi++) {
        int mf = (NMF == 2) ? mi : 1;
#pragma unroll
        for (int r = 0; r < 4; r++) {
          float sa = __shfl(scs[mi], (lane & 0x30) | (lg * 4 + r));
#pragma unroll
          for (int f = 0; f < 8; f++) acc[mf][f][r] *= sa;
        }
      }
    }

    bf16x8 pf[NMF][2];
#pragma unroll
    for (int mi = 0; mi < NMF; mi++) {
      int mf = (NMF == 2) ? mi : 1;
      float rs = 0.f;
#pragma unroll
      for (int kf = 0; kf < 4; kf++)
#pragma unroll
        for (int r = 0; r < 4; r++) {
          float pv = __builtin_amdgcn_exp2f((sv[mi][kf][r] - m_r[mf]) * SL2E);
          sv[mi][kf][r] = pv;
          rs += pv;
        }
      l_r[mf] += rs;  // deferred: cross-lane reduce moved to epilogue
#pragma unroll
      for (int ks2 = 0; ks2 < 2; ks2++) {
        bf16x8 t2;
#pragma unroll
        for (int r = 0; r < 4; r++) {
          t2[r] = (__bf16)sv[mi][2 * ks2][r];
          t2[4 + r] = (__bf16)sv[mi][2 * ks2 + 1][r];
        }
        pf[mi][ks2] = t2;
      }
    }

    __builtin_amdgcn_s_setprio(1);
#pragma unroll
    for (int ks2 = 0; ks2 < 2; ks2++)
#pragma unroll
      for (int f = 0; f < 8; f++) {
        bf16x8 vf = *(const bf16x8*)&Vl[bufIdx][vidx(f * 16 + lr, ks2 * 64 + lg * 16)];
#pragma unroll
        for (int mi = 0; mi < NMF; mi++) {
          int mf = (NMF == 2) ? mi : 1;
          acc[mf][f] = __builtin_amdgcn_mfma_f32_16x16x32_bf16(pf[mi][ks2], vf, acc[mf][f], 0, 0, 0);
        }
      }
    __builtin_amdgcn_s_setprio(0);
  };

  int ntB = 2 * (15 - p) + 2;  // shared K/V sweep length (big side)
  stage(0, 0);                 // 8 loads in flight
  int cur = 0;

  for (int t = 0; t < ntB; t++) {
    int kv0 = t * 64;
    if (t + 1 < ntB) {
      stage(cur ^ 1, (t + 1) * 64);                     // +8 loads (16 outstanding)
      asm volatile("s_waitcnt vmcnt(8)" ::: "memory");  // confirm prev tile's 8
    } else {
      asm volatile("s_waitcnt vmcnt(0)" ::: "memory");  // last tile: full drain
    }
    asm volatile("s_barrier" ::: "memory");             // raw: no vmcnt drain
    __builtin_amdgcn_sched_barrier(0);

    bool actS = (kv0 <= q0s + 15);  // wave-uniform
    bool actB = (kv0 <= q0b + 15);
    bool mS = (kv0 + 63 > q0s);
    bool mB = (kv0 + 63 > q0b);
    if (actS) {
      if (mS | mB) tileCompute(kv0, cur, std::integral_constant<int, 2>{},
                               std::integral_constant<int, 1>{});
      else tileCompute(kv0, cur, std::integral_constant<int, 2>{},
                       std::integral_constant<int, 0>{});
    } else if (actB) {
      if (mB) tileCompute(kv0, cur, std::integral_constant<int, 1>{},
                          std::integral_constant<int, 1>{});
      else tileCompute(kv0, cur, std::integral_constant<int, 1>{},
                       std::integral_constant<int, 0>{});
    }

    asm volatile("s_barrier" ::: "memory");             // readers done before next stage
    cur ^= 1;
  }

#pragma unroll
  for (int mf = 0; mf < 2; mf++) {
    int base = mf ? q0b : q0s;
    float lsum = l_r[mf];
    lsum += __shfl_xor(lsum, 16);
    lsum += __shfl_xor(lsum, 32);
    float invl = 1.0f / lsum;
#pragma unroll
    for (int r = 0; r < 4; r++) {
      float ia = __shfl(invl, (lane & 0x30) | (lg * 4 + r));
      int rowg = b * S_LEN + base + lg * 4 + r;
#pragma unroll
      for (int f = 0; f < 8; f++) {
        int colg = h * DKH + f * 16 + lr;
        ctx[(size_t)rowg * DM + colg] = f2bf(acc[mf][f][r] * ia);
      }
    }
  }
}

extern "C" void kernel_launch(void* const* d_in, const int* in_sizes, int n_in,
                              void* d_out, int out_size, void* d_ws, size_t ws_size,
                              hipStream_t stream) {
  const float* x = (const float*)d_in[0];
  const float* Wq = (const float*)d_in[1];
  const float* Wk = (const float*)d_in[2];
  const float* Wv = (const float*)d_in[3];
  const float* Wo = (const float*)d_in[4];
  float* out = (float*)d_out;

  char* ws = (char*)d_ws;
  size_t off = 0;
  auto alloc = [&](size_t bytes) -> char* {
    char* p = ws + off;
    off += (bytes + 255) & ~(size_t)255;
    return p;
  };
  u16* xb = (u16*)alloc((size_t)NROWS * DM * 2);     // reused as ctx
  u16* wqkv = (u16*)alloc((size_t)3 * DM * DM * 2);  // [Wq;Wk;Wv] rows
  u16* wob = (u16*)alloc((size_t)DM * DM * 2);
  u16* Qb = (u16*)alloc((size_t)NROWS * DM * 2);
  u16* Kb = (u16*)alloc((size_t)NROWS * DM * 2);
  u16* Vtb = (u16*)alloc((size_t)NROWS * DM * 2);
  float2* ctab = (float2*)alloc((size_t)S_LEN * 64 * 8);
  u16* ctx = xb;

  hipFuncSetAttribute((const void*)gemm256_kernel<3, 2>,
                      hipFuncAttributeMaxDynamicSharedMemorySize, 65536 + 2 * 192 * 128);
  hipFuncSetAttribute((const void*)gemm256_kernel<2, 0>,
                      hipFuncAttributeMaxDynamicSharedMemorySize, 65536 + 2 * 128 * 128);

  cast_all_kernel<<<2048, 256, 0, stream>>>(x, Wq, Wk, Wv, Wo, xb, wqkv, wob);
  rope_table_kernel<<<(S_LEN * 64 + 255) / 256, 256, 0, stream>>>(ctab);

  // fused QKV projection + RoPE + V-transpose (r8/r10 best: BN=192, 512 blocks)
  gemm256_kernel<3, 2><<<dim3(3 * DM / 192, NROWS / 256), 512, 65536 + 2 * 192 * 128, stream>>>(
      xb, wqkv, Qb, Kb, Vtb, ctab, NROWS, 3 * DM, DM);

  // paired-tile attention: 32 bh x 8 pairs x 2 halves = 512 blocks, all co-resident
  attn_kernel<<<dim3(NB * NH, 8, 2), 256, 0, stream>>>(Qb, Kb, Vtb, ctx);

  // output projection (r8/r10 best: BN=128, 256 blocks)
  gemm256_kernel<2, 0><<<dim3(DM / 128, NROWS / 256), 512, 65536 + 2 * 128 * 128, stream>>>(
      ctx, wob, out, nullptr, nullptr, nullptr, NROWS, DM, DM);
}